// Round 5
// baseline (404.251 us; speedup 1.0000x reference)
//
#include <hip/hip_runtime.h>
#include <stdint.h>
#include <stddef.h>

#define MM 512
#define NN 512
#define EE 256
#define HH 16
#define DD 16

typedef __bf16 bf16x8 __attribute__((ext_vector_type(8)));
typedef float f32x4 __attribute__((ext_vector_type(4)));

static __device__ __forceinline__ bf16x8 bzero8() {
  bf16x8 z;
#pragma unroll
  for (int i = 0; i < 8; ++i) z[i] = (__bf16)0.0f;
  return z;
}

static __device__ __forceinline__ bf16x8 cvt8(const float* __restrict__ p) {
  const float4 u = *(const float4*)p;
  const float4 v = *(const float4*)(p + 4);
  bf16x8 r;
  r[0] = (__bf16)u.x; r[1] = (__bf16)u.y; r[2] = (__bf16)u.z; r[3] = (__bf16)u.w;
  r[4] = (__bf16)v.x; r[5] = (__bf16)v.y; r[6] = (__bf16)v.z; r[7] = (__bf16)v.w;
  return r;
}

static __device__ __forceinline__ unsigned short f2b(float f) {
  union { __bf16 h; unsigned short u; } cv;
  cv.h = (__bf16)f;
  return cv.u;
}

static __device__ __forceinline__ float b2f(unsigned short u) {
  union { unsigned int i; float f; } cv;
  cv.i = ((unsigned int)u) << 16;
  return cv.f;
}

// raw v_exp_f32: computes 2^x (1/ln2 folded into MLP coefficients)
static __device__ __forceinline__ float fexp2(float x) {
  float r;
  asm("v_exp_f32 %0, %1" : "=v"(r) : "v"(x));
  return r;
}

// packed bf16 convert: dst.lo = bf16(lo), dst.hi = bf16(hi)
static __device__ __forceinline__ unsigned int cvtpk(float lo, float hi) {
  unsigned int r;
  asm("v_cvt_pk_bf16_f32 %0, %1, %2" : "=v"(r) : "v"(lo), "v"(hi));
  return r;
}

static __device__ __forceinline__ float sload(const float* p) {
  return __int_as_float(__builtin_amdgcn_readfirstlane(__float_as_int(*p)));
}

// Grid barrier: all 1024 blocks co-resident by construction (4 blocks/CU x 256
// CUs exactly). cnt/flag zeroed by a captured hipMemsetAsync before launch.
static __device__ __forceinline__ void grid_barrier(unsigned int* cnt,
                                                    unsigned int* flag,
                                                    unsigned int n) {
  __syncthreads();
  if (threadIdx.x == 0) {
    __threadfence();                       // release: block's stores visible
    if (atomicAdd(cnt, 1u) == n - 1u) {    // device-scope by default
      __hip_atomic_store(flag, 1u, __ATOMIC_RELEASE, __HIP_MEMORY_SCOPE_AGENT);
    } else {
      while (__hip_atomic_load(flag, __ATOMIC_ACQUIRE,
                               __HIP_MEMORY_SCOPE_AGENT) == 0u) {
        __builtin_amdgcn_s_sleep(8);
      }
    }
    __threadfence();                       // acquire side
  }
  __syncthreads();
}

// ---------------------------------------------------------------------------
// One kernel, three phases, two grid barriers.
// Phase A: projections (832 of 1024 blocks). Phase B: fused attention (all).
// Phase C: out = A @ Wout^T hi/lo MFMA (512 blocks).
// ---------------------------------------------------------------------------
__global__ __launch_bounds__(256, 4) void fused_kernel(
    const float* __restrict__ Xq, const float* __restrict__ Xkv,
    const float* __restrict__ dmat,
    const float* __restrict__ Wq, const float* __restrict__ Wkv,
    const float* __restrict__ W1, const float* __restrict__ b1v,
    const float* __restrict__ W2, const float* __restrict__ Wout,
    unsigned short* __restrict__ Qs, unsigned short* __restrict__ Ks,
    unsigned short* __restrict__ Vt,
    unsigned short* __restrict__ Ahi, unsigned short* __restrict__ Alo,
    unsigned short* __restrict__ Whi, unsigned short* __restrict__ Wlo,
    float* __restrict__ out, unsigned int* __restrict__ bar) {
  __shared__ unsigned short P[32][520];   // bf16 probs; pvred aliased later
  __shared__ float red[4][32];            // per-wave row sums
  float (*pvred)[2][16][16] = (float (*)[2][16][16]) & P[0][0];  // 8KB alias

  const int bid = blockIdx.x;
  const int tid = threadIdx.x, w = tid >> 6, l = tid & 63;
  const int lg = l >> 4, lr = l & 15;

  // ===================== Phase A: projections =====================
  if (bid < 832) {
    if (bid < 768) {
      const bool isQ = bid < 256;
      const int id = isQ ? bid : bid - 256;
      const int bx = id & 63, by = id >> 6;
      const int t0 = bx * 32 + (w & 1) * 16;
      const int n0 = by * 64 + (w >> 1) * 32;
      const float* X = isQ ? Xq : Xkv;
      const float* W = isQ ? Wq : Wkv;
      f32x4 acc0 = {0.f, 0.f, 0.f, 0.f}, acc1 = {0.f, 0.f, 0.f, 0.f};
#pragma unroll
      for (int kc = 0; kc < EE; kc += 32) {
        const int k = kc + lg * 8;
        bf16x8 a  = cvt8(X + (size_t)(t0 + lr) * EE + k);
        bf16x8 b0 = cvt8(W + (size_t)(n0 + lr) * EE + k);
        bf16x8 b1 = cvt8(W + (size_t)(n0 + 16 + lr) * EE + k);
        acc0 = __builtin_amdgcn_mfma_f32_16x16x32_bf16(a, b0, acc0, 0, 0, 0);
        acc1 = __builtin_amdgcn_mfma_f32_16x16x32_bf16(a, b1, acc1, 0, 0, 0);
      }
      if (isQ) {
#pragma unroll
        for (int r = 0; r < 4; ++r) {
          const int t = t0 + 4 * lg + r, b = t >> 9, m = t & 511;
          const int j0 = n0 + lr, j1 = j0 + 16;
          Qs[((size_t)(b * HH + (j0 >> 4)) * MM + m) * DD + (j0 & 15)] = f2b(acc0[r] * 0.25f);
          Qs[((size_t)(b * HH + (j1 >> 4)) * MM + m) * DD + (j1 & 15)] = f2b(acc1[r] * 0.25f);
        }
      } else {
#pragma unroll
        for (int r = 0; r < 4; ++r) {
          const int t = t0 + 4 * lg + r, b = t >> 9, n = t & 511;
#pragma unroll
          for (int fi = 0; fi < 2; ++fi) {
            const int j = n0 + lr + fi * 16;
            const float v = fi ? acc1[r] : acc0[r];
            if (j < 256) {
              Ks[((size_t)(b * HH + (j >> 4)) * NN + n) * DD + (j & 15)] = f2b(v);
            } else {
              const int jj = j - 256;
              Vt[((size_t)(b * HH + (jj >> 4)) * DD + (jj & 15)) * NN + n] = f2b(v);
            }
          }
        }
      }
    } else {
      const int base = ((bid - 768) * 256 + tid) * 4;
      const float4 v = *(const float4*)(Wout + base);
      float c4[4] = {v.x, v.y, v.z, v.w};
#pragma unroll
      for (int i = 0; i < 4; ++i) {
        const unsigned short hb = f2b(c4[i]);
        Whi[base + i] = hb;
        Wlo[base + i] = f2b(c4[i] - b2f(hb));
      }
    }
  }

  grid_barrier(bar + 0, bar + 16, 1024u);

  // ===================== Phase B: fused attention =====================
  {
    const int mt = bid & 15, hh = (bid >> 4) & 15, b = bid >> 8;
    const int m0 = mt * 32;
    const int n0 = w * 128;

    const unsigned short* Qbase = Qs + ((size_t)(b * HH + hh) * MM + m0) * DD;
    const unsigned short* Kbase = Ks + (size_t)(b * HH + hh) * NN * DD;
    const unsigned short* Vbase = Vt + (size_t)(b * HH + hh) * DD * NN;
    const float* dbase = dmat + (size_t)b * MM * NN;

    // MLP coefficients (block-uniform). relu(x)=(x+|x|)/2, fold 0.5*W2 and
    // 1/ln2 into wk; wk|ak s + ck d + bk| = wkp*|s + ckp*d + bkp|.
    float ckp[16], bkp[16], wkp[16];
    float Ac = 0.f, Cc = 0.f;
    const float hiln2 = 0.5f * 1.4426950408889634f;
#pragma unroll
    for (int k = 0; k < 16; ++k) {
      const float ak = sload(W1 + hh * 32 + k);
      const float ck = sload(W1 + hh * 32 + 16 + k);
      const float bk = sload(b1v + hh * 16 + k);
      const float wk = hiln2 * sload(W2 + hh * 16 + k);
      Ac += wk * ak;
      Cc += wk * ck;
      const float ra = 1.0f / ak;
      ckp[k] = ck * ra;
      bkp[k] = bk * ra;
      wkp[k] = wk * fabsf(ak);
    }

    bf16x8 qb[2];
#pragma unroll
    for (int mb = 0; mb < 2; ++mb) {
      qb[mb] = bzero8();
      if (lg < 2) qb[mb] = *(const bf16x8*)(Qbase + (mb * 16 + lr) * DD + lg * 8);
    }

    const f32x4 zf = {0.f, 0.f, 0.f, 0.f};
    float psum[2] = {0.f, 0.f};

#pragma unroll
    for (int nb = 0; nb < 8; ++nb) {
      // swapped QK^T: C = S^T, row = n (4lg+r), col = m (lr)
      bf16x8 ka = bzero8();
      if (lg < 2)
        ka = *(const bf16x8*)(Kbase + (size_t)(n0 + nb * 16 + lr) * DD + lg * 8);
      f32x4 cc[2];
      cc[0] = __builtin_amdgcn_mfma_f32_16x16x32_bf16(ka, qb[0], zf, 0, 0, 0);
      cc[1] = __builtin_amdgcn_mfma_f32_16x16x32_bf16(ka, qb[1], zf, 0, 0, 0);
#pragma unroll
      for (int mb = 0; mb < 2; ++mb) {
        const int mrow = m0 + mb * 16 + lr;
        const int ncol = n0 + nb * 16 + 4 * lg;
        const float4 dv = *(const float4*)(dbase + (size_t)mrow * NN + ncol);
        float ev[4];
#pragma unroll
        for (int r = 0; r < 4; ++r) {
          const float s = cc[mb][r];
          const float d = (r == 0) ? dv.x : (r == 1) ? dv.y : (r == 2) ? dv.z : dv.w;
          float acc = fmaf(Ac, s, Cc * d);
#pragma unroll
          for (int k = 0; k < 16; ++k)
            acc = fmaf(wkp[k], fabsf(s + fmaf(ckp[k], d, bkp[k])), acc);
          const float e = fexp2(acc);   // no max-subtraction: |mixed| bounded
          psum[mb] += e;
          ev[r] = e;
        }
        uint2 u;
        u.x = cvtpk(ev[0], ev[1]);
        u.y = cvtpk(ev[2], ev[3]);
        *(uint2*)&P[mb * 16 + lr][n0 + nb * 16 + 4 * lg] = u;
      }
    }

#pragma unroll
    for (int mb = 0; mb < 2; ++mb) {
      psum[mb] += __shfl_xor(psum[mb], 16);
      psum[mb] += __shfl_xor(psum[mb], 32);
      if (lg == 0) red[w][mb * 16 + lr] = psum[mb];
    }

    // PV over this wave's own n-range (self-written P rows)
    f32x4 pv[2];
    pv[0] = zf; pv[1] = zf;
#pragma unroll
    for (int kb = 0; kb < 4; ++kb) {
      const bf16x8 vb = *(const bf16x8*)(Vbase + (size_t)lr * NN + (n0 + kb * 32 + lg * 8));
#pragma unroll
      for (int mb = 0; mb < 2; ++mb) {
        const bf16x8 pa = *(const bf16x8*)(&P[mb * 16 + lr][n0 + kb * 32 + lg * 8]);
        pv[mb] = __builtin_amdgcn_mfma_f32_16x16x32_bf16(pa, vb, pv[mb], 0, 0, 0);
      }
    }
    __syncthreads();   // all P reads complete before pvred aliases onto P
#pragma unroll
    for (int mb = 0; mb < 2; ++mb)
#pragma unroll
      for (int r = 0; r < 4; ++r) pvred[w][mb][4 * lg + r][lr] = pv[mb][r];
    __syncthreads();

    for (int i = tid; i < 512; i += 256) {
      const int mr = i >> 4, dd = i & 15;
      const float s = pvred[0][mr >> 4][mr & 15][dd] + pvred[1][mr >> 4][mr & 15][dd] +
                      pvred[2][mr >> 4][mr & 15][dd] + pvred[3][mr >> 4][mr & 15][dd];
      const float rs = red[0][mr] + red[1][mr] + red[2][mr] + red[3][mr];
      const float val = s / rs;
      const unsigned short hb = f2b(val);
      const size_t o = ((size_t)(b * MM) + m0 + mr) * EE + hh * DD + dd;
      Ahi[o] = hb;
      Alo[o] = f2b(val - b2f(hb));
    }
  }

  grid_barrier(bar + 32, bar + 48, 1024u);

  // ===================== Phase C: out = A @ Wout^T (hi/lo MFMA) ==============
  if (bid < 512) {
    const int t0 = (bid & 127) * 16;                 // 128 row-tiles of 16
    const int n0 = (bid >> 7) * 64 + w * 16;         // 4 col-tiles of 64
    f32x4 acc = {0.f, 0.f, 0.f, 0.f};
#pragma unroll
    for (int kc = 0; kc < EE; kc += 32) {
      const int k = kc + lg * 8;
      const bf16x8 ah = *(const bf16x8*)(Ahi + (size_t)(t0 + lr) * EE + k);
      const bf16x8 al = *(const bf16x8*)(Alo + (size_t)(t0 + lr) * EE + k);
      const bf16x8 bh = *(const bf16x8*)(Whi + (size_t)(n0 + lr) * EE + k);
      const bf16x8 bl = *(const bf16x8*)(Wlo + (size_t)(n0 + lr) * EE + k);
      acc = __builtin_amdgcn_mfma_f32_16x16x32_bf16(ah, bh, acc, 0, 0, 0);
      acc = __builtin_amdgcn_mfma_f32_16x16x32_bf16(al, bh, acc, 0, 0, 0);
      acc = __builtin_amdgcn_mfma_f32_16x16x32_bf16(ah, bl, acc, 0, 0, 0);
    }
#pragma unroll
    for (int r = 0; r < 4; ++r)
      out[(size_t)(t0 + 4 * lg + r) * EE + n0 + lr] = acc[r];
  }
}

// ---------------------------------------------------------------------------
extern "C" void kernel_launch(void* const* d_in, const int* in_sizes, int n_in,
                              void* d_out, int out_size, void* d_ws, size_t ws_size,
                              hipStream_t stream) {
  const float* q_input  = (const float*)d_in[0];
  const float* kv_input = (const float*)d_in[1];
  const float* dmat     = (const float*)d_in[2];
  const float* Wq       = (const float*)d_in[3];
  const float* Wkv      = (const float*)d_in[4];
  const float* W1       = (const float*)d_in[5];
  const float* b1       = (const float*)d_in[6];
  const float* W2       = (const float*)d_in[7];
  // d_in[8] = mix_b2: per-row constant inside softmax -> no effect, unused
  const float* Wout     = (const float*)d_in[9];
  float* out = (float*)d_out;

  char* ws = (char*)d_ws;
  unsigned short* Qs  = (unsigned short*)(ws);                        // 1 MB bf16 [B][H][M][D]
  unsigned short* Ks  = (unsigned short*)(ws + (1u << 20));           // 1 MB bf16 [B][H][N][D]
  unsigned short* Vt  = (unsigned short*)(ws + (2u << 20));           // 1 MB bf16 [B][H][D][N]
  unsigned short* Ahi = (unsigned short*)(ws + (3u << 20));           // 1 MB bf16 [B*M][E]
  unsigned short* Alo = (unsigned short*)(ws + (4u << 20));           // 1 MB bf16 [B*M][E]
  unsigned short* Whi = (unsigned short*)(ws + (5u << 20));           // 128 KB
  unsigned short* Wlo = (unsigned short*)(ws + (5u << 20) + (1u << 17)); // 128 KB
  unsigned int*   bar = (unsigned int*)(ws + (8u << 20));             // 256 B barrier state

  hipMemsetAsync(bar, 0, 256, stream);   // zero barrier state each replay (captures as a node)

  void* args[] = {
      (void*)&q_input, (void*)&kv_input, (void*)&dmat,
      (void*)&Wq, (void*)&Wkv, (void*)&W1, (void*)&b1, (void*)&W2, (void*)&Wout,
      (void*)&Qs, (void*)&Ks, (void*)&Vt, (void*)&Ahi, (void*)&Alo,
      (void*)&Whi, (void*)&Wlo, (void*)&out, (void*)&bar};
  (void)args;
  fused_kernel<<<dim3(1024), dim3(256), 0, stream>>>(
      q_input, kv_input, dmat, Wq, Wkv, W1, b1, W2, Wout,
      Qs, Ks, Vt, Ahi, Alo, Whi, Wlo, out, bar);
}

// Round 6
// 130.944 us; speedup vs baseline: 3.0872x; 3.0872x over previous
//
#include <hip/hip_runtime.h>
#include <stdint.h>
#include <stddef.h>

#define MM 512
#define NN 512
#define EE 256
#define HH 16
#define DD 16

typedef __bf16 bf16x8 __attribute__((ext_vector_type(8)));
typedef float f32x4 __attribute__((ext_vector_type(4)));

static __device__ __forceinline__ bf16x8 bzero8() {
  bf16x8 z;
#pragma unroll
  for (int i = 0; i < 8; ++i) z[i] = (__bf16)0.0f;
  return z;
}

static __device__ __forceinline__ bf16x8 cvt8(const float* __restrict__ p) {
  const float4 u = *(const float4*)p;
  const float4 v = *(const float4*)(p + 4);
  bf16x8 r;
  r[0] = (__bf16)u.x; r[1] = (__bf16)u.y; r[2] = (__bf16)u.z; r[3] = (__bf16)u.w;
  r[4] = (__bf16)v.x; r[5] = (__bf16)v.y; r[6] = (__bf16)v.z; r[7] = (__bf16)v.w;
  return r;
}

static __device__ __forceinline__ unsigned short f2b(float f) {
  union { __bf16 h; unsigned short u; } cv;
  cv.h = (__bf16)f;
  return cv.u;
}

static __device__ __forceinline__ float b2f(unsigned short u) {
  union { unsigned int i; float f; } cv;
  cv.i = ((unsigned int)u) << 16;
  return cv.f;
}

// raw v_exp_f32: computes 2^x (1/ln2 folded into MLP coefficients)
static __device__ __forceinline__ float fexp2(float x) {
  float r;
  asm("v_exp_f32 %0, %1" : "=v"(r) : "v"(x));
  return r;
}

// packed bf16 convert: dst.lo = bf16(lo), dst.hi = bf16(hi)
static __device__ __forceinline__ unsigned int cvtpk(float lo, float hi) {
  unsigned int r;
  asm("v_cvt_pk_bf16_f32 %0, %1, %2" : "=v"(r) : "v"(lo), "v"(hi));
  return r;
}

static __device__ __forceinline__ float sload(const float* p) {
  return __int_as_float(__builtin_amdgcn_readfirstlane(__float_as_int(*p)));
}

// ---------------------------------------------------------------------------
// Fused projections. blockIdx.y: 0-3 -> Q proj, 4-11 -> KV proj, 12 -> Wout split
// (exact round-2 structure, part of the 63.8us baseline)
// ---------------------------------------------------------------------------
__global__ __launch_bounds__(256) void proj_all_kernel(
    const float* __restrict__ Xq, const float* __restrict__ Xkv,
    const float* __restrict__ Wq, const float* __restrict__ Wkv,
    const float* __restrict__ Wout,
    unsigned short* __restrict__ Qs, unsigned short* __restrict__ Ks,
    unsigned short* __restrict__ Vt,
    unsigned short* __restrict__ Whi, unsigned short* __restrict__ Wlo) {
  const int by = blockIdx.y;
  const int tid = threadIdx.x;

  if (by == 12) {
    const int base = (blockIdx.x * 256 + tid) * 4;
    const float4 v = *(const float4*)(Wout + base);
    float c4[4] = {v.x, v.y, v.z, v.w};
#pragma unroll
    for (int i = 0; i < 4; ++i) {
      const unsigned short hb = f2b(c4[i]);
      Whi[base + i] = hb;
      Wlo[base + i] = f2b(c4[i] - b2f(hb));
    }
    return;
  }

  const int w = tid >> 6, l = tid & 63;
  const int lg = l >> 4, lr = l & 15;
  const int t0 = blockIdx.x * 32 + (w & 1) * 16;

  if (by < 4) {
    const int n0 = by * 64 + (w >> 1) * 32;
    f32x4 acc0 = {0.f, 0.f, 0.f, 0.f}, acc1 = {0.f, 0.f, 0.f, 0.f};
#pragma unroll
    for (int kc = 0; kc < EE; kc += 32) {
      const int k = kc + lg * 8;
      bf16x8 a  = cvt8(Xq + (size_t)(t0 + lr) * EE + k);
      bf16x8 b0 = cvt8(Wq + (size_t)(n0 + lr) * EE + k);
      bf16x8 b1 = cvt8(Wq + (size_t)(n0 + 16 + lr) * EE + k);
      acc0 = __builtin_amdgcn_mfma_f32_16x16x32_bf16(a, b0, acc0, 0, 0, 0);
      acc1 = __builtin_amdgcn_mfma_f32_16x16x32_bf16(a, b1, acc1, 0, 0, 0);
    }
#pragma unroll
    for (int r = 0; r < 4; ++r) {
      const int t = t0 + 4 * lg + r, b = t >> 9, m = t & 511;
      const int j0 = n0 + lr, j1 = j0 + 16;
      Qs[((size_t)(b * HH + (j0 >> 4)) * MM + m) * DD + (j0 & 15)] = f2b(acc0[r] * 0.25f);
      Qs[((size_t)(b * HH + (j1 >> 4)) * MM + m) * DD + (j1 & 15)] = f2b(acc1[r] * 0.25f);
    }
  } else {
    const int n0 = (by - 4) * 64 + (w >> 1) * 32;
    f32x4 acc0 = {0.f, 0.f, 0.f, 0.f}, acc1 = {0.f, 0.f, 0.f, 0.f};
#pragma unroll
    for (int kc = 0; kc < EE; kc += 32) {
      const int k = kc + lg * 8;
      bf16x8 a  = cvt8(Xkv + (size_t)(t0 + lr) * EE + k);
      bf16x8 b0 = cvt8(Wkv + (size_t)(n0 + lr) * EE + k);
      bf16x8 b1 = cvt8(Wkv + (size_t)(n0 + 16 + lr) * EE + k);
      acc0 = __builtin_amdgcn_mfma_f32_16x16x32_bf16(a, b0, acc0, 0, 0, 0);
      acc1 = __builtin_amdgcn_mfma_f32_16x16x32_bf16(a, b1, acc1, 0, 0, 0);
    }
#pragma unroll
    for (int r = 0; r < 4; ++r) {
      const int t = t0 + 4 * lg + r, b = t >> 9, n = t & 511;
#pragma unroll
      for (int fi = 0; fi < 2; ++fi) {
        const int j = n0 + lr + fi * 16;
        const float v = fi ? acc1[r] : acc0[r];
        if (j < 256) {
          Ks[((size_t)(b * HH + (j >> 4)) * NN + n) * DD + (j & 15)] = f2b(v);
        } else {
          const int jj = j - 256;
          Vt[((size_t)(b * HH + (jj >> 4)) * DD + (jj & 15)) * NN + n] = f2b(v);
        }
      }
    }
  }
}

// ---------------------------------------------------------------------------
// Fused attention (round-4 body). DIAGNOSTIC: executes the body `reps` times
// with identical writes (idempotent; host passes 2) so the dispatch exceeds
// the 40us memset rows and becomes visible in rocprof top-5.
// ---------------------------------------------------------------------------
__global__ __launch_bounds__(256, 4) void attn_kernel(
    const unsigned short* __restrict__ Qs, const unsigned short* __restrict__ Ks,
    const unsigned short* __restrict__ Vt, const float* __restrict__ dmat,
    const float* __restrict__ W1, const float* __restrict__ b1v,
    const float* __restrict__ W2,
    unsigned short* __restrict__ Ahi, unsigned short* __restrict__ Alo,
    int reps) {
  __shared__ unsigned short P[32][520];   // bf16 probs; pvred aliased later
  __shared__ float red[4][32];            // per-wave row sums
  float (*pvred)[2][16][16] = (float (*)[2][16][16]) & P[0][0];  // 8KB alias

  const int tid = threadIdx.x, w = tid >> 6, l = tid & 63;
  const int lg = l >> 4, lr = l & 15;
  const int bid = blockIdx.x;
  const int mt = bid & 15, hh = (bid >> 4) & 15, b = bid >> 8;
  const int m0 = mt * 32;
  const int n0 = w * 128;

  const unsigned short* Qbase = Qs + ((size_t)(b * HH + hh) * MM + m0) * DD;
  const unsigned short* Kbase = Ks + (size_t)(b * HH + hh) * NN * DD;
  const unsigned short* Vbase = Vt + (size_t)(b * HH + hh) * DD * NN;
  const float* dbase = dmat + (size_t)b * MM * NN;

  // MLP coefficients (block-uniform). relu(x)=(x+|x|)/2, fold 0.5*W2 and
  // 1/ln2 into wk; wk|ak s + ck d + bk| = wkp*|s + ckp*d + bkp|.
  float ckp[16], bkp[16], wkp[16];
  float Ac = 0.f, Cc = 0.f;
  const float hiln2 = 0.5f * 1.4426950408889634f;
#pragma unroll
  for (int k = 0; k < 16; ++k) {
    const float ak = sload(W1 + hh * 32 + k);
    const float ck = sload(W1 + hh * 32 + 16 + k);
    const float bk = sload(b1v + hh * 16 + k);
    const float wk = hiln2 * sload(W2 + hh * 16 + k);
    Ac += wk * ak;
    Cc += wk * ck;
    const float ra = 1.0f / ak;
    ckp[k] = ck * ra;
    bkp[k] = bk * ra;
    wkp[k] = wk * fabsf(ak);
  }

#pragma clang loop unroll(disable)
  for (int rep = 0; rep < reps; ++rep) {
    __syncthreads();   // protect P-writes from prior rep's aliased pvred reads

    bf16x8 qb[2];
#pragma unroll
    for (int mb = 0; mb < 2; ++mb) {
      qb[mb] = bzero8();
      if (lg < 2) qb[mb] = *(const bf16x8*)(Qbase + (mb * 16 + lr) * DD + lg * 8);
    }

    const f32x4 zf = {0.f, 0.f, 0.f, 0.f};
    float psum[2] = {0.f, 0.f};

#pragma unroll
    for (int nb = 0; nb < 8; ++nb) {
      // swapped QK^T: C = S^T, row = n (4lg+r), col = m (lr)
      bf16x8 ka = bzero8();
      if (lg < 2)
        ka = *(const bf16x8*)(Kbase + (size_t)(n0 + nb * 16 + lr) * DD + lg * 8);
      f32x4 cc[2];
      cc[0] = __builtin_amdgcn_mfma_f32_16x16x32_bf16(ka, qb[0], zf, 0, 0, 0);
      cc[1] = __builtin_amdgcn_mfma_f32_16x16x32_bf16(ka, qb[1], zf, 0, 0, 0);
#pragma unroll
      for (int mb = 0; mb < 2; ++mb) {
        const int mrow = m0 + mb * 16 + lr;
        const int ncol = n0 + nb * 16 + 4 * lg;
        const float4 dv = *(const float4*)(dbase + (size_t)mrow * NN + ncol);
        float ev[4];
#pragma unroll
        for (int r = 0; r < 4; ++r) {
          const float s = cc[mb][r];
          const float d = (r == 0) ? dv.x : (r == 1) ? dv.y : (r == 2) ? dv.z : dv.w;
          float acc = fmaf(Ac, s, Cc * d);
#pragma unroll
          for (int k = 0; k < 16; ++k)
            acc = fmaf(wkp[k], fabsf(s + fmaf(ckp[k], d, bkp[k])), acc);
          const float e = fexp2(acc);   // no max-subtraction: |mixed| bounded
          psum[mb] += e;
          ev[r] = e;
        }
        uint2 u;
        u.x = cvtpk(ev[0], ev[1]);
        u.y = cvtpk(ev[2], ev[3]);
        *(uint2*)&P[mb * 16 + lr][n0 + nb * 16 + 4 * lg] = u;
      }
    }

#pragma unroll
    for (int mb = 0; mb < 2; ++mb) {
      psum[mb] += __shfl_xor(psum[mb], 16);
      psum[mb] += __shfl_xor(psum[mb], 32);
      if (lg == 0) red[w][mb * 16 + lr] = psum[mb];
    }

    // PV over this wave's own n-range (self-written P rows)
    f32x4 pv[2];
    pv[0] = zf; pv[1] = zf;
#pragma unroll
    for (int kb = 0; kb < 4; ++kb) {
      const bf16x8 vb = *(const bf16x8*)(Vbase + (size_t)lr * NN + (n0 + kb * 32 + lg * 8));
#pragma unroll
      for (int mb = 0; mb < 2; ++mb) {
        const bf16x8 pa = *(const bf16x8*)(&P[mb * 16 + lr][n0 + kb * 32 + lg * 8]);
        pv[mb] = __builtin_amdgcn_mfma_f32_16x16x32_bf16(pa, vb, pv[mb], 0, 0, 0);
      }
    }
    __syncthreads();   // all P reads complete before pvred aliases onto P
#pragma unroll
    for (int mb = 0; mb < 2; ++mb)
#pragma unroll
      for (int r = 0; r < 4; ++r) pvred[w][mb][4 * lg + r][lr] = pv[mb][r];
    __syncthreads();

    for (int i = tid; i < 512; i += 256) {
      const int mr = i >> 4, dd = i & 15;
      const float s = pvred[0][mr >> 4][mr & 15][dd] + pvred[1][mr >> 4][mr & 15][dd] +
                      pvred[2][mr >> 4][mr & 15][dd] + pvred[3][mr >> 4][mr & 15][dd];
      const float rs = red[0][mr] + red[1][mr] + red[2][mr] + red[3][mr];
      const float val = s / rs;
      const unsigned short hb = f2b(val);
      const size_t o = ((size_t)(b * MM) + m0 + mr) * EE + hh * DD + dd;
      Ahi[o] = hb;
      Alo[o] = f2b(val - b2f(hb));
    }
  }
}

// ---------------------------------------------------------------------------
// Final projection via bf16 MFMA with hi/lo split (~fp32 accuracy):
// out = Ahi@Whi^T + Alo@Whi^T + Ahi@Wlo^T  (exact round-2 structure)
// ---------------------------------------------------------------------------
__global__ __launch_bounds__(256) void out_gemm_kernel(
    const unsigned short* __restrict__ Ahi, const unsigned short* __restrict__ Alo,
    const unsigned short* __restrict__ Whi, const unsigned short* __restrict__ Wlo,
    float* __restrict__ out) {
  const int tid = threadIdx.x, w = tid >> 6, l = tid & 63;
  const int lg = l >> 4, lr = l & 15;
  const int t0 = blockIdx.x * 32 + (w & 1) * 16;
  const int n0 = blockIdx.y * 64 + (w >> 1) * 32;
  f32x4 acc0 = {0.f, 0.f, 0.f, 0.f}, acc1 = {0.f, 0.f, 0.f, 0.f};
#pragma unroll
  for (int kc = 0; kc < EE; kc += 32) {
    const int k = kc + lg * 8;
    const bf16x8 ah = *(const bf16x8*)(Ahi + (size_t)(t0 + lr) * EE + k);
    const bf16x8 al = *(const bf16x8*)(Alo + (size_t)(t0 + lr) * EE + k);
    const bf16x8 bh0 = *(const bf16x8*)(Whi + (size_t)(n0 + lr) * EE + k);
    const bf16x8 bh1 = *(const bf16x8*)(Whi + (size_t)(n0 + 16 + lr) * EE + k);
    const bf16x8 bl0 = *(const bf16x8*)(Wlo + (size_t)(n0 + lr) * EE + k);
    const bf16x8 bl1 = *(const bf16x8*)(Wlo + (size_t)(n0 + 16 + lr) * EE + k);
    acc0 = __builtin_amdgcn_mfma_f32_16x16x32_bf16(ah, bh0, acc0, 0, 0, 0);
    acc0 = __builtin_amdgcn_mfma_f32_16x16x32_bf16(al, bh0, acc0, 0, 0, 0);
    acc0 = __builtin_amdgcn_mfma_f32_16x16x32_bf16(ah, bl0, acc0, 0, 0, 0);
    acc1 = __builtin_amdgcn_mfma_f32_16x16x32_bf16(ah, bh1, acc1, 0, 0, 0);
    acc1 = __builtin_amdgcn_mfma_f32_16x16x32_bf16(al, bh1, acc1, 0, 0, 0);
    acc1 = __builtin_amdgcn_mfma_f32_16x16x32_bf16(ah, bl1, acc1, 0, 0, 0);
  }
#pragma unroll
  for (int r = 0; r < 4; ++r) {
    const int row = t0 + 4 * lg + r;
    out[(size_t)row * EE + n0 + lr] = acc0[r];
    out[(size_t)row * EE + n0 + 16 + lr] = acc1[r];
  }
}

// ---------------------------------------------------------------------------
extern "C" void kernel_launch(void* const* d_in, const int* in_sizes, int n_in,
                              void* d_out, int out_size, void* d_ws, size_t ws_size,
                              hipStream_t stream) {
  const float* q_input  = (const float*)d_in[0];
  const float* kv_input = (const float*)d_in[1];
  const float* dmat     = (const float*)d_in[2];
  const float* Wq       = (const float*)d_in[3];
  const float* Wkv      = (const float*)d_in[4];
  const float* W1       = (const float*)d_in[5];
  const float* b1       = (const float*)d_in[6];
  const float* W2       = (const float*)d_in[7];
  // d_in[8] = mix_b2: per-row constant inside softmax -> no effect, unused
  const float* Wout     = (const float*)d_in[9];
  float* out = (float*)d_out;

  char* ws = (char*)d_ws;
  unsigned short* Qs  = (unsigned short*)(ws);                        // 1 MB bf16 [B][H][M][D]
  unsigned short* Ks  = (unsigned short*)(ws + (1u << 20));           // 1 MB bf16 [B][H][N][D]
  unsigned short* Vt  = (unsigned short*)(ws + (2u << 20));           // 1 MB bf16 [B][H][D][N]
  unsigned short* Ahi = (unsigned short*)(ws + (3u << 20));           // 1 MB bf16 [B*M][E]
  unsigned short* Alo = (unsigned short*)(ws + (4u << 20));           // 1 MB bf16 [B*M][E]
  unsigned short* Whi = (unsigned short*)(ws + (5u << 20));           // 128 KB
  unsigned short* Wlo = (unsigned short*)(ws + (5u << 20) + (1u << 17)); // 128 KB

  proj_all_kernel<<<dim3(64, 13), 256, 0, stream>>>(q_input, kv_input, Wq, Wkv, Wout,
                                                    Qs, Ks, Vt, Whi, Wlo);
  // DIAGNOSTIC: reps=2 doubles attn duration (idempotent writes) so it shows
  // up in rocprof top-5 above the 40us harness memsets.
  attn_kernel<<<dim3(1024), 256, 0, stream>>>(Qs, Ks, Vt, dmat, W1, b1, W2,
                                              Ahi, Alo, 2);
  out_gemm_kernel<<<dim3(64, 4), 256, 0, stream>>>(Ahi, Alo, Whi, Wlo, out);
}

// Round 7
// 63.350 us; speedup vs baseline: 6.3812x; 2.0670x over previous
//
#include <hip/hip_runtime.h>
#include <stdint.h>
#include <stddef.h>

#define MM 512
#define NN 512
#define EE 256
#define HH 16
#define DD 16

typedef __bf16 bf16x8 __attribute__((ext_vector_type(8)));
typedef float f32x4 __attribute__((ext_vector_type(4)));

static __device__ __forceinline__ bf16x8 bzero8() {
  bf16x8 z;
#pragma unroll
  for (int i = 0; i < 8; ++i) z[i] = (__bf16)0.0f;
  return z;
}

static __device__ __forceinline__ bf16x8 cvt8(const float* __restrict__ p) {
  const float4 u = *(const float4*)p;
  const float4 v = *(const float4*)(p + 4);
  bf16x8 r;
  r[0] = (__bf16)u.x; r[1] = (__bf16)u.y; r[2] = (__bf16)u.z; r[3] = (__bf16)u.w;
  r[4] = (__bf16)v.x; r[5] = (__bf16)v.y; r[6] = (__bf16)v.z; r[7] = (__bf16)v.w;
  return r;
}

static __device__ __forceinline__ unsigned short f2b(float f) {
  union { __bf16 h; unsigned short u; } cv;
  cv.h = (__bf16)f;
  return cv.u;
}

static __device__ __forceinline__ float b2f(unsigned short u) {
  union { unsigned int i; float f; } cv;
  cv.i = ((unsigned int)u) << 16;
  return cv.f;
}

// raw v_exp_f32: computes 2^x (1/ln2 folded into MLP coefficients)
static __device__ __forceinline__ float fexp2(float x) {
  float r;
  asm("v_exp_f32 %0, %1" : "=v"(r) : "v"(x));
  return r;
}

// packed bf16 convert: dst.lo = bf16(lo), dst.hi = bf16(hi)
static __device__ __forceinline__ unsigned int cvtpk(float lo, float hi) {
  unsigned int r;
  asm("v_cvt_pk_bf16_f32 %0, %1, %2" : "=v"(r) : "v"(lo), "v"(hi));
  return r;
}

static __device__ __forceinline__ float sload(const float* p) {
  return __int_as_float(__builtin_amdgcn_readfirstlane(__float_as_int(*p)));
}

// ---------------------------------------------------------------------------
// Fused projections. blockIdx.y: 0-3 -> Q proj, 4-11 -> KV proj, 12 -> Wout split
// (round-2 structure, part of the 63.8us baseline)
// ---------------------------------------------------------------------------
__global__ __launch_bounds__(256) void proj_all_kernel(
    const float* __restrict__ Xq, const float* __restrict__ Xkv,
    const float* __restrict__ Wq, const float* __restrict__ Wkv,
    const float* __restrict__ Wout,
    unsigned short* __restrict__ Qs, unsigned short* __restrict__ Ks,
    unsigned short* __restrict__ Vt,
    unsigned short* __restrict__ Whi, unsigned short* __restrict__ Wlo) {
  const int by = blockIdx.y;
  const int tid = threadIdx.x;

  if (by == 12) {
    const int base = (blockIdx.x * 256 + tid) * 4;
    const float4 v = *(const float4*)(Wout + base);
    float c4[4] = {v.x, v.y, v.z, v.w};
#pragma unroll
    for (int i = 0; i < 4; ++i) {
      const unsigned short hb = f2b(c4[i]);
      Whi[base + i] = hb;
      Wlo[base + i] = f2b(c4[i] - b2f(hb));
    }
    return;
  }

  const int w = tid >> 6, l = tid & 63;
  const int lg = l >> 4, lr = l & 15;
  const int t0 = blockIdx.x * 32 + (w & 1) * 16;

  if (by < 4) {
    const int n0 = by * 64 + (w >> 1) * 32;
    f32x4 acc0 = {0.f, 0.f, 0.f, 0.f}, acc1 = {0.f, 0.f, 0.f, 0.f};
#pragma unroll
    for (int kc = 0; kc < EE; kc += 32) {
      const int k = kc + lg * 8;
      bf16x8 a  = cvt8(Xq + (size_t)(t0 + lr) * EE + k);
      bf16x8 b0 = cvt8(Wq + (size_t)(n0 + lr) * EE + k);
      bf16x8 b1 = cvt8(Wq + (size_t)(n0 + 16 + lr) * EE + k);
      acc0 = __builtin_amdgcn_mfma_f32_16x16x32_bf16(a, b0, acc0, 0, 0, 0);
      acc1 = __builtin_amdgcn_mfma_f32_16x16x32_bf16(a, b1, acc1, 0, 0, 0);
    }
#pragma unroll
    for (int r = 0; r < 4; ++r) {
      const int t = t0 + 4 * lg + r, b = t >> 9, m = t & 511;
      const int j0 = n0 + lr, j1 = j0 + 16;
      Qs[((size_t)(b * HH + (j0 >> 4)) * MM + m) * DD + (j0 & 15)] = f2b(acc0[r] * 0.25f);
      Qs[((size_t)(b * HH + (j1 >> 4)) * MM + m) * DD + (j1 & 15)] = f2b(acc1[r] * 0.25f);
    }
  } else {
    const int n0 = (by - 4) * 64 + (w >> 1) * 32;
    f32x4 acc0 = {0.f, 0.f, 0.f, 0.f}, acc1 = {0.f, 0.f, 0.f, 0.f};
#pragma unroll
    for (int kc = 0; kc < EE; kc += 32) {
      const int k = kc + lg * 8;
      bf16x8 a  = cvt8(Xkv + (size_t)(t0 + lr) * EE + k);
      bf16x8 b0 = cvt8(Wkv + (size_t)(n0 + lr) * EE + k);
      bf16x8 b1 = cvt8(Wkv + (size_t)(n0 + 16 + lr) * EE + k);
      acc0 = __builtin_amdgcn_mfma_f32_16x16x32_bf16(a, b0, acc0, 0, 0, 0);
      acc1 = __builtin_amdgcn_mfma_f32_16x16x32_bf16(a, b1, acc1, 0, 0, 0);
    }
#pragma unroll
    for (int r = 0; r < 4; ++r) {
      const int t = t0 + 4 * lg + r, b = t >> 9, n = t & 511;
#pragma unroll
      for (int fi = 0; fi < 2; ++fi) {
        const int j = n0 + lr + fi * 16;
        const float v = fi ? acc1[r] : acc0[r];
        if (j < 256) {
          Ks[((size_t)(b * HH + (j >> 4)) * NN + n) * DD + (j & 15)] = f2b(v);
        } else {
          const int jj = j - 256;
          Vt[((size_t)(b * HH + (jj >> 4)) * DD + (jj & 15)) * NN + n] = f2b(v);
        }
      }
    }
  }
}

// ---------------------------------------------------------------------------
// Fused attention (round-4 structure). Anti-spill round 7:
//  - __launch_bounds__(256,2): VGPR cap 256 (was implicitly 64 -> scratch)
//  - ckv/bkv pinned to VGPRs (inner fma all-VGPR; wkp stays SGPR = 1/instr)
// ---------------------------------------------------------------------------
__global__ __launch_bounds__(256, 2) void attn_kernel(
    const unsigned short* __restrict__ Qs, const unsigned short* __restrict__ Ks,
    const unsigned short* __restrict__ Vt, const float* __restrict__ dmat,
    const float* __restrict__ W1, const float* __restrict__ b1v,
    const float* __restrict__ W2,
    unsigned short* __restrict__ Ahi, unsigned short* __restrict__ Alo) {
  __shared__ unsigned short P[32][520];   // bf16 probs; pvred aliased later
  __shared__ float red[4][32];            // per-wave row sums
  float (*pvred)[2][16][16] = (float (*)[2][16][16]) & P[0][0];  // 8KB alias

  const int tid = threadIdx.x, w = tid >> 6, l = tid & 63;
  const int lg = l >> 4, lr = l & 15;
  const int bid = blockIdx.x;
  const int mt = bid & 15, hh = (bid >> 4) & 15, b = bid >> 8;
  const int m0 = mt * 32;
  const int n0 = w * 128;

  const unsigned short* Qbase = Qs + ((size_t)(b * HH + hh) * MM + m0) * DD;
  const unsigned short* Kbase = Ks + (size_t)(b * HH + hh) * NN * DD;
  const unsigned short* Vbase = Vt + (size_t)(b * HH + hh) * DD * NN;
  const float* dbase = dmat + (size_t)b * MM * NN;

  // MLP coefficients. relu(x)=(x+|x|)/2, fold 0.5*W2 and 1/ln2 into wk;
  // wk|ak s + ck d + bk| = wkp*|s + ckp*d + bkp|.
  // ckv/bkv pinned to VGPRs (avoid 2-SGPR operands -> per-use v_mov);
  // wkp/Ac/Cc uniform SGPR (1 SGPR per VALU instr is free).
  float ckv[16], bkv[16], wkp[16];
  float Ac = 0.f, Cc = 0.f;
  const float hiln2 = 0.5f * 1.4426950408889634f;
#pragma unroll
  for (int k = 0; k < 16; ++k) {
    const float ak = sload(W1 + hh * 32 + k);
    const float ck = sload(W1 + hh * 32 + 16 + k);
    const float bk = sload(b1v + hh * 16 + k);
    const float wk = hiln2 * sload(W2 + hh * 16 + k);
    Ac += wk * ak;
    Cc += wk * ck;
    const float ra = 1.0f / ak;
    ckv[k] = ck * ra;
    bkv[k] = bk * ra;
    wkp[k] = wk * fabsf(ak);
    asm volatile("" : "+v"(ckv[k]));   // pin to VGPR
    asm volatile("" : "+v"(bkv[k]));   // pin to VGPR
  }

  bf16x8 qb[2];
#pragma unroll
  for (int mb = 0; mb < 2; ++mb) {
    qb[mb] = bzero8();
    if (lg < 2) qb[mb] = *(const bf16x8*)(Qbase + (mb * 16 + lr) * DD + lg * 8);
  }

  const f32x4 zf = {0.f, 0.f, 0.f, 0.f};
  float psum[2] = {0.f, 0.f};

#pragma unroll
  for (int nb = 0; nb < 8; ++nb) {
    // swapped QK^T: C = S^T, row = n (4lg+r), col = m (lr)
    bf16x8 ka = bzero8();
    if (lg < 2)
      ka = *(const bf16x8*)(Kbase + (size_t)(n0 + nb * 16 + lr) * DD + lg * 8);
    f32x4 cc[2];
    cc[0] = __builtin_amdgcn_mfma_f32_16x16x32_bf16(ka, qb[0], zf, 0, 0, 0);
    cc[1] = __builtin_amdgcn_mfma_f32_16x16x32_bf16(ka, qb[1], zf, 0, 0, 0);
#pragma unroll
    for (int mb = 0; mb < 2; ++mb) {
      const int mrow = m0 + mb * 16 + lr;
      const int ncol = n0 + nb * 16 + 4 * lg;
      const float4 dv = *(const float4*)(dbase + (size_t)mrow * NN + ncol);
      float ev[4];
#pragma unroll
      for (int r = 0; r < 4; ++r) {
        const float s = cc[mb][r];
        const float d = (r == 0) ? dv.x : (r == 1) ? dv.y : (r == 2) ? dv.z : dv.w;
        float acc = fmaf(Ac, s, Cc * d);
#pragma unroll
        for (int k = 0; k < 16; ++k) {
          const float t = fmaf(ckv[k], d, bkv[k]);   // all-VGPR fma
          acc = fmaf(wkp[k], fabsf(s + t), acc);     // SGPR coeff + abs modifier
        }
        const float e = fexp2(acc);   // no max-subtraction: |mixed| bounded
        psum[mb] += e;
        ev[r] = e;
      }
      uint2 u;
      u.x = cvtpk(ev[0], ev[1]);
      u.y = cvtpk(ev[2], ev[3]);
      *(uint2*)&P[mb * 16 + lr][n0 + nb * 16 + 4 * lg] = u;
    }
  }

#pragma unroll
  for (int mb = 0; mb < 2; ++mb) {
    psum[mb] += __shfl_xor(psum[mb], 16);
    psum[mb] += __shfl_xor(psum[mb], 32);
    if (lg == 0) red[w][mb * 16 + lr] = psum[mb];
  }

  // PV over this wave's own n-range (self-written P rows)
  f32x4 pv[2];
  pv[0] = zf; pv[1] = zf;
#pragma unroll
  for (int kb = 0; kb < 4; ++kb) {
    const bf16x8 vb = *(const bf16x8*)(Vbase + (size_t)lr * NN + (n0 + kb * 32 + lg * 8));
#pragma unroll
    for (int mb = 0; mb < 2; ++mb) {
      const bf16x8 pa = *(const bf16x8*)(&P[mb * 16 + lr][n0 + kb * 32 + lg * 8]);
      pv[mb] = __builtin_amdgcn_mfma_f32_16x16x32_bf16(pa, vb, pv[mb], 0, 0, 0);
    }
  }
  __syncthreads();   // all P reads complete before pvred aliases onto P
#pragma unroll
  for (int mb = 0; mb < 2; ++mb)
#pragma unroll
    for (int r = 0; r < 4; ++r) pvred[w][mb][4 * lg + r][lr] = pv[mb][r];
  __syncthreads();

  for (int i = tid; i < 512; i += 256) {
    const int mr = i >> 4, dd = i & 15;
    const float s = pvred[0][mr >> 4][mr & 15][dd] + pvred[1][mr >> 4][mr & 15][dd] +
                    pvred[2][mr >> 4][mr & 15][dd] + pvred[3][mr >> 4][mr & 15][dd];
    const float rs = red[0][mr] + red[1][mr] + red[2][mr] + red[3][mr];
    const float val = s / rs;
    const unsigned short hb = f2b(val);
    const size_t o = ((size_t)(b * MM) + m0 + mr) * EE + hh * DD + dd;
    Ahi[o] = hb;
    Alo[o] = f2b(val - b2f(hb));
  }
}

// ---------------------------------------------------------------------------
// Final projection via bf16 MFMA with hi/lo split (~fp32 accuracy):
// out = Ahi@Whi^T + Alo@Whi^T + Ahi@Wlo^T  (round-2 structure)
// ---------------------------------------------------------------------------
__global__ __launch_bounds__(256) void out_gemm_kernel(
    const unsigned short* __restrict__ Ahi, const unsigned short* __restrict__ Alo,
    const unsigned short* __restrict__ Whi, const unsigned short* __restrict__ Wlo,
    float* __restrict__ out) {
  const int tid = threadIdx.x, w = tid >> 6, l = tid & 63;
  const int lg = l >> 4, lr = l & 15;
  const int t0 = blockIdx.x * 32 + (w & 1) * 16;
  const int n0 = blockIdx.y * 64 + (w >> 1) * 32;
  f32x4 acc0 = {0.f, 0.f, 0.f, 0.f}, acc1 = {0.f, 0.f, 0.f, 0.f};
#pragma unroll
  for (int kc = 0; kc < EE; kc += 32) {
    const int k = kc + lg * 8;
    const bf16x8 ah = *(const bf16x8*)(Ahi + (size_t)(t0 + lr) * EE + k);
    const bf16x8 al = *(const bf16x8*)(Alo + (size_t)(t0 + lr) * EE + k);
    const bf16x8 bh0 = *(const bf16x8*)(Whi + (size_t)(n0 + lr) * EE + k);
    const bf16x8 bh1 = *(const bf16x8*)(Whi + (size_t)(n0 + 16 + lr) * EE + k);
    const bf16x8 bl0 = *(const bf16x8*)(Wlo + (size_t)(n0 + lr) * EE + k);
    const bf16x8 bl1 = *(const bf16x8*)(Wlo + (size_t)(n0 + 16 + lr) * EE + k);
    acc0 = __builtin_amdgcn_mfma_f32_16x16x32_bf16(ah, bh0, acc0, 0, 0, 0);
    acc0 = __builtin_amdgcn_mfma_f32_16x16x32_bf16(al, bh0, acc0, 0, 0, 0);
    acc0 = __builtin_amdgcn_mfma_f32_16x16x32_bf16(ah, bl0, acc0, 0, 0, 0);
    acc1 = __builtin_amdgcn_mfma_f32_16x16x32_bf16(ah, bh1, acc1, 0, 0, 0);
    acc1 = __builtin_amdgcn_mfma_f32_16x16x32_bf16(al, bh1, acc1, 0, 0, 0);
    acc1 = __builtin_amdgcn_mfma_f32_16x16x32_bf16(ah, bl1, acc1, 0, 0, 0);
  }
#pragma unroll
  for (int r = 0; r < 4; ++r) {
    const int row = t0 + 4 * lg + r;
    out[(size_t)row * EE + n0 + lr] = acc0[r];
    out[(size_t)row * EE + n0 + 16 + lr] = acc1[r];
  }
}

// ---------------------------------------------------------------------------
extern "C" void kernel_launch(void* const* d_in, const int* in_sizes, int n_in,
                              void* d_out, int out_size, void* d_ws, size_t ws_size,
                              hipStream_t stream) {
  const float* q_input  = (const float*)d_in[0];
  const float* kv_input = (const float*)d_in[1];
  const float* dmat     = (const float*)d_in[2];
  const float* Wq       = (const float*)d_in[3];
  const float* Wkv      = (const float*)d_in[4];
  const float* W1       = (const float*)d_in[5];
  const float* b1       = (const float*)d_in[6];
  const float* W2       = (const float*)d_in[7];
  // d_in[8] = mix_b2: per-row constant inside softmax -> no effect, unused
  const float* Wout     = (const float*)d_in[9];
  float* out = (float*)d_out;

  char* ws = (char*)d_ws;
  unsigned short* Qs  = (unsigned short*)(ws);                        // 1 MB bf16 [B][H][M][D]
  unsigned short* Ks  = (unsigned short*)(ws + (1u << 20));           // 1 MB bf16 [B][H][N][D]
  unsigned short* Vt  = (unsigned short*)(ws + (2u << 20));           // 1 MB bf16 [B][H][D][N]
  unsigned short* Ahi = (unsigned short*)(ws + (3u << 20));           // 1 MB bf16 [B*M][E]
  unsigned short* Alo = (unsigned short*)(ws + (4u << 20));           // 1 MB bf16 [B*M][E]
  unsigned short* Whi = (unsigned short*)(ws + (5u << 20));           // 128 KB
  unsigned short* Wlo = (unsigned short*)(ws + (5u << 20) + (1u << 17)); // 128 KB

  proj_all_kernel<<<dim3(64, 13), 256, 0, stream>>>(q_input, kv_input, Wq, Wkv, Wout,
                                                    Qs, Ks, Vt, Whi, Wlo);
  attn_kernel<<<dim3(1024), 256, 0, stream>>>(Qs, Ks, Vt, dmat, W1, b1, W2,
                                              Ahi, Alo);
  out_gemm_kernel<<<dim3(64, 4), 256, 0, stream>>>(Ahi, Alo, Whi, Wlo, out);
}